// Round 12
// baseline (180.664 us; speedup 1.0000x reference)
//
#include <hip/hip_runtime.h>

#define NJ 128   // images
#define NI 128   // captions
#define NR 36    // regions
#define NW 32    // words
#define ND 1024  // feature dim

#define LAM_SM 9.0f
#define LAM_LSE 6.0f
#define MARGIN 0.2f
#define EPSF 1e-8f

typedef __attribute__((ext_vector_type(8))) short s16x8;
typedef __attribute__((ext_vector_type(4))) float f32x4;

#define IM_ROWS (NJ * NR)          // 4608
#define S_ROWS  (NI * NW)          // 4096
#define ALL_ROWS (IM_ROWS + S_ROWS)
#define IM_ELEMS (IM_ROWS * ND)
#define S_ELEMS  (S_ROWS * ND)
#define GSW_ELEMS (NJ * 48 * 64)   // bf16, swizzled, zero-padded

// pair7 LDS (dynamic, 45056 B) -> 2 blocks/CU:
//   stage: A 288x128B [0,36864) + B 64x128B [36864,45056)
//   epilogue overlay: E 8 waves x 2048 [0,16384) | Gd 2x6144 [16384,28672)
//     NBp [4 wn][288] f32 [28672,33280) | NB [2 caps][288] [33280,35584)
//     simS [4 wn][16] [35584,35840)
#define BOFF 36864
#define GD_OFF 16384
#define NBP_OFF 28672
#define NB2_OFF 33280
#define SIM_OFF 35584
#define SMEM_TOTAL 45056
#define GRAM_SMEM 98304

__device__ __forceinline__ unsigned short f2bf(float x) {
    unsigned u = __float_as_uint(x);
    return (unsigned short)((u + 0x7FFFu + ((u >> 16) & 1u)) >> 16);
}
__device__ __forceinline__ unsigned pack2bf(float x, float y) {
    return (unsigned)f2bf(x) | ((unsigned)f2bf(y) << 16);
}
__device__ __forceinline__ float bf2f(unsigned v) {
    return __uint_as_float((v & 0xffffu) << 16);
}
__device__ __forceinline__ void gload16(const void* g, void* l) {
    __builtin_amdgcn_global_load_lds((const __attribute__((address_space(1))) unsigned int*)g,
                                     (__attribute__((address_space(3))) unsigned int*)l, 16, 0, 0);
}

// ---- merged f32->bf16 convert + 128B-window swizzle (key=row&7) + fused wnorm ----
__global__ __launch_bounds__(256) void cvtswz2_kernel(const float* __restrict__ im,
                                                      const float* __restrict__ s,
                                                      unsigned short* __restrict__ dst,
                                                      float* __restrict__ w1) {
    __shared__ float part[4];
    const int tid = threadIdx.x;
    int idx = blockIdx.x * 256 + tid;
    int row = idx >> 7, cw = idx & 127;
    int wd = cw >> 3, p = cw & 7;
    int sk = wd * 64 + ((p ^ (row & 7)) * 8);
    const float* srow = (row < IM_ROWS) ? (im + (size_t)row * ND)
                                        : (s + (size_t)(row - IM_ROWS) * ND);
    float4 v0 = *(const float4*)(srow + sk);
    float4 v1 = *(const float4*)(srow + sk + 4);
    ushort4 o0, o1;
    o0.x = f2bf(v0.x); o0.y = f2bf(v0.y); o0.z = f2bf(v0.z); o0.w = f2bf(v0.w);
    o1.x = f2bf(v1.x); o1.y = f2bf(v1.y); o1.z = f2bf(v1.z); o1.w = f2bf(v1.w);
    ((ushort4*)dst)[(size_t)idx * 2] = o0;
    ((ushort4*)dst)[(size_t)idx * 2 + 1] = o1;
    float ss = v0.x * v0.x + v0.y * v0.y + v0.z * v0.z + v0.w * v0.w +
               v1.x * v1.x + v1.y * v1.y + v1.z * v1.z + v1.w * v1.w;
    ss += __shfl_xor(ss, 1);  ss += __shfl_xor(ss, 2);  ss += __shfl_xor(ss, 4);
    ss += __shfl_xor(ss, 8);  ss += __shfl_xor(ss, 16); ss += __shfl_xor(ss, 32);
    if ((tid & 63) == 0) part[tid >> 6] = ss;
    __syncthreads();
    if ((tid & 127) == 0 && row >= IM_ROWS) {
        int h = tid >> 7;
        w1[row - IM_ROWS] = sqrtf(part[h * 2] + part[h * 2 + 1]);
    }
}

// ---- Gram via MFMA, 4-wave K-split (R10-proven) ----
__global__ __launch_bounds__(256) void gram3_kernel(const unsigned short* __restrict__ imsw,
                                                    unsigned short* __restrict__ Gsw) {
    extern __shared__ char gsm[];
    const int j = blockIdx.x;
    const int tid = threadIdx.x;
    const int wv = tid >> 6, l = tid & 63;
    const int grp = l >> 4, lw = l & 15;
    char* reg = gsm + wv * 24576;

#pragma unroll
    for (int u = 0; u < 6; ++u)
        *(int4*)(reg + 36 * 512 + (l + u * 64) * 16) = make_int4(0, 0, 0, 0);
    {
        const char* src = (const char*)imsw + ((size_t)j * 36 + (l >> 5)) * 2048 +
                          wv * 512 + (l & 31) * 16;
#pragma unroll
        for (int c = 0; c < 18; ++c)
            gload16(src + (size_t)c * 4096, reg + c * 1024);
    }
    asm volatile("s_waitcnt vmcnt(0)" ::: "memory");

    const int keyadj = (j & 1) * 4;
    f32x4 acc[3][3];
#pragma unroll
    for (int m = 0; m < 3; ++m)
#pragma unroll
        for (int n = 0; n < 3; ++n) acc[m][n] = (f32x4){0.f, 0.f, 0.f, 0.f};

#pragma unroll
    for (int ks = 0; ks < 8; ++ks) {
        const int widx = ks >> 1;
        const int swzg = ((((ks & 1) * 4 + grp) ^ ((lw + keyadj) & 7)) << 4);
        s16x8 fr[3];
#pragma unroll
        for (int m = 0; m < 3; ++m)
            fr[m] = *(const s16x8*)(reg + (m * 16 + lw) * 512 + widx * 128 + swzg);
#pragma unroll
        for (int m = 0; m < 3; ++m)
#pragma unroll
            for (int n = 0; n < 3; ++n)
                acc[m][n] = __builtin_amdgcn_mfma_f32_16x16x32_bf16(fr[m], fr[n], acc[m][n], 0, 0, 0);
    }
    __syncthreads();
    float* Gt = (float*)(gsm + wv * 9984);
#pragma unroll
    for (int m = 0; m < 3; ++m)
#pragma unroll
        for (int n = 0; n < 3; ++n)
#pragma unroll
            for (int r4 = 0; r4 < 4; ++r4)
                Gt[(m * 16 + grp * 4 + r4) * 52 + n * 16 + lw] = acc[m][n][r4];
    __syncthreads();
    const float* G0 = (const float*)gsm;
    const float* G1 = (const float*)(gsm + 9984);
    const float* G2 = (const float*)(gsm + 19968);
    const float* G3 = (const float*)(gsm + 29952);
#pragma unroll
    for (int u = 0; u < 2; ++u) {
        int e = tid + u * 256;
        if (e < 384) {
            int row = e >> 3, p = e & 7;
            int k0 = (p ^ (row & 7)) * 8;
            float v[8];
#pragma unroll
            for (int i = 0; i < 8; ++i) {
                int k = k0 + i;
                v[i] = (k < 48) ? (G0[row * 52 + k] + G1[row * 52 + k] +
                                   G2[row * 52 + k] + G3[row * 52 + k]) : 0.f;
            }
            ushort4 o0, o1;
            o0.x = f2bf(v[0]); o0.y = f2bf(v[1]); o0.z = f2bf(v[2]); o0.w = f2bf(v[3]);
            o1.x = f2bf(v[4]); o1.y = f2bf(v[5]); o1.z = f2bf(v[6]); o1.w = f2bf(v[7]);
            ushort4* dp = (ushort4*)((char*)Gsw + (size_t)j * 6144 + row * 128 + p * 16);
            dp[0] = o0; dp[1] = o1;
        }
    }
}

// ---- pair7: 8 img x 2 caps, 8 waves (2M x 4N), wave tile 144x16, acc[9][1]=36 AGPR ----
// Single buffer, 45KB LDS -> 2 blocks/CU, 16 waves/CU (4 waves/SIMD; 128-VGPR budget
// via launch_bounds(512,2) which R4 showed pins the cap at 128 — demand ~120 fits).
__global__ __launch_bounds__(512, 2)
void pair7_kernel(const unsigned short* __restrict__ imsw,
                  const unsigned short* __restrict__ ssw,
                  const unsigned short* __restrict__ Gswp,
                  const float* __restrict__ w1g,
                  float* __restrict__ scores) {
    extern __shared__ char smem[];
    const int ig = blockIdx.x;   // caption pair
    const int jg = blockIdx.y;   // image octet
    const int tid = threadIdx.x;
    const int l = tid & 63, wv = tid >> 6;
    const int grp = l >> 4, lw = l & 15;
    const int wm = wv >> 2, wn = wv & 3;
    const int cap = wn >> 1, hf = wn & 1;       // caption-local, word-half

    const char* aSrc = (const char*)imsw + ((size_t)(jg * 288) + (l >> 3)) * 2048 + (l & 7) * 16;
    const char* bSrc = (const char*)ssw + ((size_t)(ig * 64) + (l >> 3)) * 2048 + (l & 7) * 16;

    f32x4 acc[9];
#pragma unroll
    for (int m = 0; m < 9; ++m) acc[m] = (f32x4){0.f, 0.f, 0.f, 0.f};

    for (int t = 0; t < 16; ++t) {
        const int k0b = t * 128;
#pragma unroll
        for (int u = 0; u < 6; ++u) {
            int c = wv + 8 * u;
            if (c < 36) gload16(aSrc + (size_t)c * 16384 + k0b, smem + c * 1024);
            else if (c < 44) gload16(bSrc + (size_t)(c - 36) * 16384 + k0b,
                                     smem + BOFF + (c - 36) * 1024);
        }
        asm volatile("s_waitcnt vmcnt(0)" ::: "memory");
        __syncthreads();
        const char* A = smem;
        const char* B = smem + BOFF;
#pragma unroll
        for (int ks = 0; ks < 2; ++ks) {
            const int swz = (((ks * 4 + grp) ^ (lw & 7)) << 4);
            s16x8 b = *(const s16x8*)(B + (wn * 16 + lw) * 128 + swz);
#pragma unroll
            for (int m = 0; m < 9; ++m) {
                s16x8 a = *(const s16x8*)(A + (wm * 144 + m * 16 + lw) * 128 + swz);
                acc[m] = __builtin_amdgcn_mfma_f32_16x16x32_bf16(a, b, acc[m], 0, 0, 0);
            }
        }
        __syncthreads();   // reads done before next-tile overwrite
    }

    // ================= epilogue =================
    char* const myE = smem + wv * 2048;                 // 16 word-rows x 128B
    float* NBp = (float*)(smem + NBP_OFF);              // [4 wn][288]
    float* NB = (float*)(smem + NB2_OFF);               // [2 cap][288]
    float* simS = (float*)(smem + SIM_OFF);             // [4 wn][16]

    auto loadGd = [&](int L) {   // 12KB: tiles for images jg*8 + {L, 4+L}
#pragma unroll
        for (int u = 0; u < 2; ++u) {
            int c = wv + 8 * u;
            if (c < 12) {
                int tile = c / 6, kb = c - tile * 6;
                gload16((const char*)Gswp + ((size_t)(jg * 8 + tile * 4 + L)) * 6144 +
                            kb * 1024 + l * 16,
                        smem + GD_OFF + c * 1024);
            }
        }
    };
    loadGd(0);

    // zero E pads (regions 36..63) for my 16 word-rows
#pragma unroll
    for (int u = 0; u < 4; ++u) {
        int e = l + u * 64;               // 224 = 16w * 14 pairs
        if (e < 224) {
            int wl = e / 14, pr = e - wl * 14 + 18;
            *(unsigned*)(myE + wl * 128 + (((pr >> 2) ^ (wl & 7)) << 4) + (pr & 3) * 4) = 0u;
        }
    }

    // P1: partial (16-word) squared norms -> NBp[wn][row]
#pragma unroll
    for (int m = 0; m < 9; ++m)
#pragma unroll
        for (int reg = 0; reg < 4; ++reg) {
            int rowL = m * 16 + grp * 4 + reg;
            float a = acc[m][reg];
            float lk = a > 0.f ? a : 0.1f * a;
            float ss = lk * lk;
            ss += __shfl_xor(ss, 1); ss += __shfl_xor(ss, 2);
            ss += __shfl_xor(ss, 4); ss += __shfl_xor(ss, 8);
            if (lw == 0) NBp[wn * 288 + wm * 144 + rowL] = ss;
        }
    __syncthreads();
    // combine halves -> NB[cap][row] (even-wn waves write their wm rows)
    if (hf == 0) {
#pragma unroll
        for (int u = 0; u < 3; ++u) {
            int e = l + u * 64;
            if (e < 144) {
                int row = wm * 144 + e;
                float ssum = NBp[wn * 288 + row] + NBp[(wn + 1) * 288 + row];
                NB[cap * 288 + row] = 1.f / (sqrtf(ssum) + EPSF);
            }
        }
    }
    __syncthreads();

    // P2: per-local-image max logit for my word (col = lw)
    float mx[4];
#pragma unroll
    for (int a = 0; a < 4; ++a) mx[a] = -1e30f;
#pragma unroll
    for (int m = 0; m < 9; ++m) {
        int rbase = m * 16 + grp * 4;
        int img = (rbase * 1821) >> 16;      // rbase / 36
        float4 iv = *(const float4*)&NB[cap * 288 + wm * 144 + rbase];
        float ivr[4] = {iv.x, iv.y, iv.z, iv.w};
        float t4 = -1e30f;
#pragma unroll
        for (int reg = 0; reg < 4; ++reg) {
            float a = acc[m][reg];
            float lk = a > 0.f ? a : 0.1f * a;
            t4 = fmaxf(t4, LAM_SM * lk * ivr[reg]);
        }
#pragma unroll
        for (int mm = 0; mm < 4; ++mm)
            mx[mm] = (img == mm) ? fmaxf(mx[mm], t4) : mx[mm];
    }
#pragma unroll
    for (int a = 0; a < 4; ++a) {
        mx[a] = fmaxf(mx[a], __shfl_xor(mx[a], 16));
        mx[a] = fmaxf(mx[a], __shfl_xor(mx[a], 32));
    }

    const float w1v = w1g[(ig * 2 + cap) * 32 + hf * 16 + lw];

#pragma unroll
    for (int L = 0; L < 4; ++L) {
        float dn = 0.f, nm = 0.f;
        // P3: image L rows are m in {2L,2L+1,2L+2} — static indices (rule #20)
#pragma unroll
        for (int mm3 = 0; mm3 < 3; ++mm3) {
            const int m = 2 * L + mm3;
            int rbase = m * 16 + grp * 4;
            int img = (rbase * 1821) >> 16;
            bool pred = (img == L);
            int rp0 = rbase - L * 36;
            float4 iv = *(const float4*)&NB[cap * 288 + wm * 144 + rbase];
            float ivr[4] = {iv.x, iv.y, iv.z, iv.w};
            float e[4];
#pragma unroll
            for (int reg = 0; reg < 4; ++reg) {
                float a = acc[m][reg];
                float lk = a > 0.f ? a : 0.1f * a;
                float tl = LAM_SM * lk * ivr[reg];
                e[reg] = pred ? __expf(tl - mx[L]) : 0.f;
                dn += e[reg];
                nm += e[reg] * a;
            }
            if (pred) {
                char* base = myE + lw * 128 + (((rp0 >> 3) ^ (lw & 7)) << 4) + (rp0 & 7) * 2;
                *(unsigned*)(base) = pack2bf(e[0], e[1]);
                *(unsigned*)(base + 4) = pack2bf(e[2], e[3]);
            }
        }
        dn += __shfl_xor(dn, 16); dn += __shfl_xor(dn, 32);
        nm += __shfl_xor(nm, 16); nm += __shfl_xor(nm, 32);

        asm volatile("s_waitcnt vmcnt(0)" ::: "memory");
        __syncthreads();                     // Gd(L) resident for all waves
        // P4: U = Gd[wm] x E ; q = sum E .* U
        const char* Gd = smem + GD_OFF + wm * 6144;
        f32x4 u[3];
#pragma unroll
        for (int m = 0; m < 3; ++m) u[m] = (f32x4){0.f, 0.f, 0.f, 0.f};
#pragma unroll
        for (int ks = 0; ks < 2; ++ks) {
            int sz2 = (((ks * 4 + grp) ^ (lw & 7)) << 4);
            s16x8 eb = *(const s16x8*)(myE + lw * 128 + (((ks * 4 + grp) ^ (lw & 7)) << 4));
#pragma unroll
            for (int m = 0; m < 3; ++m) {
                s16x8 ga = *(const s16x8*)(Gd + (m * 16 + lw) * 128 + sz2);
                u[m] = __builtin_amdgcn_mfma_f32_16x16x32_bf16(ga, eb, u[m], 0, 0, 0);
            }
        }
        float qq = 0.f;
#pragma unroll
        for (int m = 0; m < 3; ++m) {
            const char* base = myE + lw * 128;
#pragma unroll
            for (int rg = 0; rg < 4; rg += 2) {
                int rp = m * 16 + grp * 4 + rg;
                unsigned pv = *(const unsigned*)(base + (((rp >> 3) ^ (lw & 7)) << 4) + (rp & 7) * 2);
                qq += u[m][rg] * bf2f(pv) + u[m][rg + 1] * bf2f(pv >> 16);
            }
        }
        qq += __shfl_xor(qq, 16); qq += __shfl_xor(qq, 32);
        // P5: cosine sim, cross-wave-pair LSE over 32 words
        float sim = nm / fmaxf(w1v * sqrtf(fmaxf(qq, 0.f)), EPSF * dn);
        if (l < 16) simS[wn * 16 + lw] = sim;
        __syncthreads();                     // simS visible; all Gd(L)/E reads done
        if (hf == 0) {
            float s0 = simS[wn * 16 + lw];
            float s1 = simS[(wn + 1) * 16 + lw];
            float m2 = fmaxf(s0, s1);
            m2 = fmaxf(m2, __shfl_xor(m2, 1)); m2 = fmaxf(m2, __shfl_xor(m2, 2));
            m2 = fmaxf(m2, __shfl_xor(m2, 4)); m2 = fmaxf(m2, __shfl_xor(m2, 8));
            float ssum = __expf(LAM_LSE * (s0 - m2)) + __expf(LAM_LSE * (s1 - m2));
            ssum += __shfl_xor(ssum, 1); ssum += __shfl_xor(ssum, 2);
            ssum += __shfl_xor(ssum, 4); ssum += __shfl_xor(ssum, 8);
            if (l == 0)
                scores[(size_t)(jg * 8 + wm * 4 + L) * NI + ig * 2 + cap] =
                    m2 + logf(ssum) / LAM_LSE;
        }
        if (L < 3) loadGd(L + 1);           // safe: all waves past Gd(L) reads
    }
}

// ---- final hinge loss over the 128x128 score matrix ----
__global__ __launch_bounds__(256) void loss_kernel(const float* __restrict__ scores,
                                                   float* __restrict__ out) {
    __shared__ float diag[NJ];
    __shared__ float part[256];
    const int tid = threadIdx.x;
    if (tid < NJ) diag[tid] = scores[tid * NI + tid];
    __syncthreads();
    float m = 0.f;
    if (tid < 128) {
        const int a = tid;
        const float da = diag[a];
        for (int b = 0; b < NI; ++b) {
            if (b == a) continue;
            float c = MARGIN + scores[a * NI + b] - da;
            m = fmaxf(m, c);
        }
    } else {
        const int b = tid - 128;
        const float db = diag[b];
        for (int a = 0; a < NJ; ++a) {
            if (a == b) continue;
            float c = MARGIN + scores[a * NI + b] - db;
            m = fmaxf(m, c);
        }
    }
    part[tid] = m;
    __syncthreads();
    for (int st = 128; st > 0; st >>= 1) {
        if (tid < st) part[tid] += part[tid + st];
        __syncthreads();
    }
    if (tid == 0) out[0] = part[0];
}

extern "C" void kernel_launch(void* const* d_in, const int* in_sizes, int n_in,
                              void* d_out, int out_size, void* d_ws, size_t ws_size,
                              hipStream_t stream) {
    const float* im = (const float*)d_in[0];
    const float* s = (const float*)d_in[1];

    unsigned short* imsw = (unsigned short*)d_ws;
    unsigned short* ssw = imsw + IM_ELEMS;
    unsigned short* Gswp = ssw + S_ELEMS;
    float* w1 = (float*)(Gswp + GSW_ELEMS);
    float* scores = w1 + S_ROWS;

    hipFuncSetAttribute((const void*)pair7_kernel,
                        hipFuncAttributeMaxDynamicSharedMemorySize, SMEM_TOTAL);
    hipFuncSetAttribute((const void*)gram3_kernel,
                        hipFuncAttributeMaxDynamicSharedMemorySize, GRAM_SMEM);

    cvtswz2_kernel<<<dim3(ALL_ROWS / 2), dim3(256), 0, stream>>>(im, s, imsw, w1);
    gram3_kernel<<<dim3(NJ), dim3(256), GRAM_SMEM, stream>>>(imsw, Gswp);
    pair7_kernel<<<dim3(NI / 2, NJ / 8), dim3(512), SMEM_TOTAL, stream>>>(imsw, ssw, Gswp, w1, scores);
    loss_kernel<<<dim3(1), dim3(256), 0, stream>>>(scores, (float*)d_out);
}

// Round 13
// 122.418 us; speedup vs baseline: 1.4758x; 1.4758x over previous
//
#include <hip/hip_runtime.h>

#define NJ 128   // images
#define NI 128   // captions
#define NR 36    // regions
#define NW 32    // words
#define ND 1024  // feature dim

#define LAM_SM 9.0f
#define LAM_LSE 6.0f
#define MARGIN 0.2f
#define EPSF 1e-8f

typedef __attribute__((ext_vector_type(8))) short s16x8;
typedef __attribute__((ext_vector_type(4))) float f32x4;

#define IM_ROWS (NJ * NR)          // 4608
#define S_ROWS  (NI * NW)          // 4096
#define ALL_ROWS (IM_ROWS + S_ROWS)
#define IM_ELEMS (IM_ROWS * ND)
#define S_ELEMS  (S_ROWS * ND)
#define GSW_ELEMS (NJ * 48 * 64)   // bf16, swizzled, zero-padded

// pair8 LDS map (dynamic, 106496 B) — R8/R11-proven layout:
//   buf0 [0,53248): A 288x128B [0,36864) + B 128x128B [36864,53248)
//   buf1 [53248,106496): same
//   epilogue overlay: Gd 8x6144 [0,49152) | E 8 slots x 4096 [53248,86016)
//                     | NB f32 [4 caps][288] [86016,90624)
#define BUFSZ 53248
#define BOFF 36864
#define E_OFF 53248
#define NB_OFF 86016
#define SMEM_TOTAL 106496
#define GRAM_SMEM 98304

__device__ __forceinline__ unsigned short f2bf(float x) {
    unsigned u = __float_as_uint(x);
    return (unsigned short)((u + 0x7FFFu + ((u >> 16) & 1u)) >> 16);
}
__device__ __forceinline__ unsigned pack2bf(float x, float y) {
    return (unsigned)f2bf(x) | ((unsigned)f2bf(y) << 16);
}
__device__ __forceinline__ float bf2f(unsigned v) {
    return __uint_as_float((v & 0xffffu) << 16);
}
__device__ __forceinline__ void gload16(const void* g, void* l) {
    __builtin_amdgcn_global_load_lds((const __attribute__((address_space(1))) unsigned int*)g,
                                     (__attribute__((address_space(3))) unsigned int*)l, 16, 0, 0);
}

// ---- merged f32->bf16 convert + 128B-window swizzle (key=row&7) + fused wnorm ----
__global__ __launch_bounds__(256) void cvtswz2_kernel(const float* __restrict__ im,
                                                      const float* __restrict__ s,
                                                      unsigned short* __restrict__ dst,
                                                      float* __restrict__ w1) {
    __shared__ float part[4];
    const int tid = threadIdx.x;
    int idx = blockIdx.x * 256 + tid;
    int row = idx >> 7, cw = idx & 127;
    int wd = cw >> 3, p = cw & 7;
    int sk = wd * 64 + ((p ^ (row & 7)) * 8);
    const float* srow = (row < IM_ROWS) ? (im + (size_t)row * ND)
                                        : (s + (size_t)(row - IM_ROWS) * ND);
    float4 v0 = *(const float4*)(srow + sk);
    float4 v1 = *(const float4*)(srow + sk + 4);
    ushort4 o0, o1;
    o0.x = f2bf(v0.x); o0.y = f2bf(v0.y); o0.z = f2bf(v0.z); o0.w = f2bf(v0.w);
    o1.x = f2bf(v1.x); o1.y = f2bf(v1.y); o1.z = f2bf(v1.z); o1.w = f2bf(v1.w);
    ((ushort4*)dst)[(size_t)idx * 2] = o0;
    ((ushort4*)dst)[(size_t)idx * 2 + 1] = o1;
    float ss = v0.x * v0.x + v0.y * v0.y + v0.z * v0.z + v0.w * v0.w +
               v1.x * v1.x + v1.y * v1.y + v1.z * v1.z + v1.w * v1.w;
    ss += __shfl_xor(ss, 1);  ss += __shfl_xor(ss, 2);  ss += __shfl_xor(ss, 4);
    ss += __shfl_xor(ss, 8);  ss += __shfl_xor(ss, 16); ss += __shfl_xor(ss, 32);
    if ((tid & 63) == 0) part[tid >> 6] = ss;
    __syncthreads();
    if ((tid & 127) == 0 && row >= IM_ROWS) {
        int h = tid >> 7;
        w1[row - IM_ROWS] = sqrtf(part[h * 2] + part[h * 2 + 1]);
    }
}

// ---- Gram via MFMA, 4-wave K-split (R10-proven) ----
__global__ __launch_bounds__(256) void gram3_kernel(const unsigned short* __restrict__ imsw,
                                                    unsigned short* __restrict__ Gsw) {
    extern __shared__ char gsm[];
    const int j = blockIdx.x;
    const int tid = threadIdx.x;
    const int wv = tid >> 6, l = tid & 63;
    const int grp = l >> 4, lw = l & 15;
    char* reg = gsm + wv * 24576;

#pragma unroll
    for (int u = 0; u < 6; ++u)
        *(int4*)(reg + 36 * 512 + (l + u * 64) * 16) = make_int4(0, 0, 0, 0);
    {
        const char* src = (const char*)imsw + ((size_t)j * 36 + (l >> 5)) * 2048 +
                          wv * 512 + (l & 31) * 16;
#pragma unroll
        for (int c = 0; c < 18; ++c)
            gload16(src + (size_t)c * 4096, reg + c * 1024);
    }
    asm volatile("s_waitcnt vmcnt(0)" ::: "memory");

    const int keyadj = (j & 1) * 4;
    f32x4 acc[3][3];
#pragma unroll
    for (int m = 0; m < 3; ++m)
#pragma unroll
        for (int n = 0; n < 3; ++n) acc[m][n] = (f32x4){0.f, 0.f, 0.f, 0.f};

#pragma unroll
    for (int ks = 0; ks < 8; ++ks) {
        const int widx = ks >> 1;
        const int swzg = ((((ks & 1) * 4 + grp) ^ ((lw + keyadj) & 7)) << 4);
        s16x8 fr[3];
#pragma unroll
        for (int m = 0; m < 3; ++m)
            fr[m] = *(const s16x8*)(reg + (m * 16 + lw) * 512 + widx * 128 + swzg);
#pragma unroll
        for (int m = 0; m < 3; ++m)
#pragma unroll
            for (int n = 0; n < 3; ++n)
                acc[m][n] = __builtin_amdgcn_mfma_f32_16x16x32_bf16(fr[m], fr[n], acc[m][n], 0, 0, 0);
    }
    __syncthreads();
    float* Gt = (float*)(gsm + wv * 9984);
#pragma unroll
    for (int m = 0; m < 3; ++m)
#pragma unroll
        for (int n = 0; n < 3; ++n)
#pragma unroll
            for (int r4 = 0; r4 < 4; ++r4)
                Gt[(m * 16 + grp * 4 + r4) * 52 + n * 16 + lw] = acc[m][n][r4];
    __syncthreads();
    const float* G0 = (const float*)gsm;
    const float* G1 = (const float*)(gsm + 9984);
    const float* G2 = (const float*)(gsm + 19968);
    const float* G3 = (const float*)(gsm + 29952);
#pragma unroll
    for (int u = 0; u < 2; ++u) {
        int e = tid + u * 256;
        if (e < 384) {
            int row = e >> 3, p = e & 7;
            int k0 = (p ^ (row & 7)) * 8;
            float v[8];
#pragma unroll
            for (int i = 0; i < 8; ++i) {
                int k = k0 + i;
                v[i] = (k < 48) ? (G0[row * 52 + k] + G1[row * 52 + k] +
                                   G2[row * 52 + k] + G3[row * 52 + k]) : 0.f;
            }
            ushort4 o0, o1;
            o0.x = f2bf(v[0]); o0.y = f2bf(v[1]); o0.z = f2bf(v[2]); o0.w = f2bf(v[3]);
            o1.x = f2bf(v[4]); o1.y = f2bf(v[5]); o1.z = f2bf(v[6]); o1.w = f2bf(v[7]);
            ushort4* dp = (ushort4*)((char*)Gsw + (size_t)j * 6144 + row * 128 + p * 16);
            dp[0] = o0; dp[1] = o1;
        }
    }
}

// ---- pair8: R11's pair4 with counted-vmcnt pipeline (T3/T4-minimum) ----
// stage 2 tiles ahead; per-iter wait only for the tile about to be computed
// (vmcnt(k_w): waves 0-3 issue 7 loads/stage, 4-7 issue 6). Raw s_barrier (no
// compiler vmcnt(0) drain). Gram prefetch replaces stage at t==14.
__global__ __attribute__((amdgpu_flat_work_group_size(512, 512)))
__attribute__((amdgpu_waves_per_eu(2, 2)))
void pair8_kernel(const unsigned short* __restrict__ imsw,
                  const unsigned short* __restrict__ ssw,
                  const unsigned short* __restrict__ Gswp,
                  const float* __restrict__ w1g,
                  float* __restrict__ scores) {
    extern __shared__ char smem[];
    const int ig = blockIdx.x;   // caption quad
    const int jg = blockIdx.y;   // image octet
    const int tid = threadIdx.x;
    const int l = tid & 63, wv = tid >> 6;
    const int grp = l >> 4, lw = l & 15;
    const int wm = wv >> 2, wn = wv & 3;

    const char* aSrc = (const char*)imsw + ((size_t)(jg * 288) + (l >> 3)) * 2048 + (l & 7) * 16;
    const char* bSrc = (const char*)ssw + ((size_t)(ig * 128) + (l >> 3)) * 2048 + (l & 7) * 16;

    f32x4 acc[9][2];
#pragma unroll
    for (int m = 0; m < 9; ++m)
#pragma unroll
        for (int n = 0; n < 2; ++n) acc[m][n] = (f32x4){0.f, 0.f, 0.f, 0.f};

    auto stage = [&](int bb, int k0b) {
        char* ab = smem + bb;
#pragma unroll
        for (int t = 0; t < 5; ++t) {
            int ii = wv + 8 * t;
            if (ii < 36) gload16(aSrc + (size_t)ii * 16384 + k0b, ab + ii * 1024);
        }
        char* bbp = smem + bb + BOFF;
#pragma unroll
        for (int t = 0; t < 2; ++t) {
            int ii = wv + 8 * t;
            gload16(bSrc + (size_t)ii * 16384 + k0b, bbp + ii * 1024);
        }
    };
    auto compute = [&](int bb) {
        const char* A = smem + bb;
        const char* B = smem + bb + BOFF;
#pragma unroll
        for (int ks = 0; ks < 2; ++ks) {
            const int swz = (((ks * 4 + grp) ^ (lw & 7)) << 4);
            s16x8 b0 = *(const s16x8*)(B + (wn * 32 + lw) * 128 + swz);
            s16x8 b1 = *(const s16x8*)(B + (wn * 32 + 16 + lw) * 128 + swz);
#pragma unroll
            for (int m = 0; m < 9; ++m) {
                s16x8 a = *(const s16x8*)(A + (wm * 144 + m * 16 + lw) * 128 + swz);
                acc[m][0] = __builtin_amdgcn_mfma_f32_16x16x32_bf16(a, b0, acc[m][0], 0, 0, 0);
                acc[m][1] = __builtin_amdgcn_mfma_f32_16x16x32_bf16(a, b1, acc[m][1], 0, 0, 0);
            }
        }
    };

    stage(0, 0);
    stage(BUFSZ, 128);
    for (int t = 0; t < 16; ++t) {
        // wait ONLY for tile t (leave tile t+1 / Gram in flight)
        if (t < 15) {
            if (wv < 4) asm volatile("s_waitcnt vmcnt(7)" ::: "memory");
            else        asm volatile("s_waitcnt vmcnt(6)" ::: "memory");
        } else {
            asm volatile("s_waitcnt vmcnt(6)" ::: "memory");   // leave Gram(6) in flight
        }
        __builtin_amdgcn_s_barrier();
        __builtin_amdgcn_sched_barrier(0);
        compute((t & 1) * BUFSZ);
        asm volatile("s_waitcnt lgkmcnt(0)" ::: "memory");
        __builtin_amdgcn_sched_barrier(0);
        __builtin_amdgcn_s_barrier();
        if (t < 14) {
            stage((t & 1) * BUFSZ, (t + 2) * 128);
        } else if (t == 14) {
            // prefetch Gram tiles for the 8 images into (dead) buf0
            const char* gB = (const char*)Gswp + (size_t)jg * 49152 + l * 16;
#pragma unroll
            for (int u = 0; u < 6; ++u) {
                int ii = wv + 8 * u;
                gload16(gB + (size_t)ii * 1024, smem + ii * 1024);
            }
        }
    }

    // ================= barrier-free per-wave epilogue (R8-proven) =================
    char* const myE = smem + E_OFF + wv * 4096;
    float* NB = (float*)(smem + NB_OFF);

    // zero E pads (regions 36..63) for my slot
#pragma unroll
    for (int u = 0; u < 7; ++u) {
        int e = l + u * 64;               // 448 = 32w * 14 pairs
        int w = e / 14, pr = e - w * 14 + 18;
        *(unsigned*)(myE + w * 128 + (((pr >> 2) ^ (w & 7)) << 4) + (pr & 3) * 4) = 0u;
    }

    // P1: inverse region norms -> NB[cap][288] (wave-local)
#pragma unroll
    for (int m = 0; m < 9; ++m)
#pragma unroll
        for (int reg = 0; reg < 4; ++reg) {
            int rowL = m * 16 + grp * 4 + reg;
            float a0 = acc[m][0][reg], a1 = acc[m][1][reg];
            float l0 = a0 > 0.f ? a0 : 0.1f * a0;
            float l1 = a1 > 0.f ? a1 : 0.1f * a1;
            float ss = l0 * l0 + l1 * l1;
            ss += __shfl_xor(ss, 1); ss += __shfl_xor(ss, 2);
            ss += __shfl_xor(ss, 4); ss += __shfl_xor(ss, 8);
            if (lw == 0)
                NB[wn * 288 + wm * 144 + rowL] = 1.f / (sqrtf(ss) + EPSF);
        }

    // P2: per-local-image per-word max logit
    float mx[4][2];
#pragma unroll
    for (int a = 0; a < 4; ++a)
#pragma unroll
        for (int b = 0; b < 2; ++b) mx[a][b] = -1e30f;
#pragma unroll
    for (int m = 0; m < 9; ++m) {
        int rbase = m * 16 + grp * 4;
        int img = (rbase * 1821) >> 16;      // rbase / 36
        float4 iv = *(const float4*)&NB[wn * 288 + wm * 144 + rbase];
        float ivr[4] = {iv.x, iv.y, iv.z, iv.w};
#pragma unroll
        for (int n = 0; n < 2; ++n) {
            float t4 = -1e30f;
#pragma unroll
            for (int reg = 0; reg < 4; ++reg) {
                float a = acc[m][n][reg];
                float lk = a > 0.f ? a : 0.1f * a;
                t4 = fmaxf(t4, LAM_SM * lk * ivr[reg]);
            }
#pragma unroll
            for (int mm = 0; mm < 4; ++mm)
                mx[mm][n] = (img == mm) ? fmaxf(mx[mm][n], t4) : mx[mm][n];
        }
    }
#pragma unroll
    for (int a = 0; a < 4; ++a)
#pragma unroll
        for (int b = 0; b < 2; ++b) {
            mx[a][b] = fmaxf(mx[a][b], __shfl_xor(mx[a][b], 16));
            mx[a][b] = fmaxf(mx[a][b], __shfl_xor(mx[a][b], 32));
        }

    float w1v[2];
#pragma unroll
    for (int n = 0; n < 2; ++n)
        w1v[n] = w1g[(ig * 4 + wn) * 32 + n * 16 + lw];

    // drain the Gram prefetch (issued at t==14; latency hidden under P1-P2)
    asm volatile("s_waitcnt vmcnt(0)" ::: "memory");
    __builtin_amdgcn_s_barrier();

#pragma unroll
    for (int L = 0; L < 4; ++L) {
        float dn[2] = {0.f, 0.f}, nm[2] = {0.f, 0.f};
        // P3: image L rows are m in {2L,2L+1,2L+2} — static indices (rule #20)
#pragma unroll
        for (int mm3 = 0; mm3 < 3; ++mm3) {
            const int m = 2 * L + mm3;
            int rbase = m * 16 + grp * 4;
            int img = (rbase * 1821) >> 16;
            bool pred = (img == L);
            int rp0 = rbase - L * 36;
            float4 iv = *(const float4*)&NB[wn * 288 + wm * 144 + rbase];
            float ivr[4] = {iv.x, iv.y, iv.z, iv.w};
#pragma unroll
            for (int n = 0; n < 2; ++n) {
                int w = n * 16 + lw;
                float e[4];
#pragma unroll
                for (int reg = 0; reg < 4; ++reg) {
                    float a = acc[m][n][reg];
                    float lk = a > 0.f ? a : 0.1f * a;
                    float tl = LAM_SM * lk * ivr[reg];
                    e[reg] = pred ? __expf(tl - mx[L][n]) : 0.f;
                    dn[n] += e[reg];
                    nm[n] += e[reg] * a;
                }
                if (pred) {
                    char* base = myE + w * 128 + (((rp0 >> 3) ^ (w & 7)) << 4) + (rp0 & 7) * 2;
                    *(unsigned*)(base) = pack2bf(e[0], e[1]);
                    *(unsigned*)(base + 4) = pack2bf(e[2], e[3]);
                }
            }
        }
#pragma unroll
        for (int n = 0; n < 2; ++n) {
            dn[n] += __shfl_xor(dn[n], 16); dn[n] += __shfl_xor(dn[n], 32);
            nm[n] += __shfl_xor(nm[n], 16); nm[n] += __shfl_xor(nm[n], 32);
        }
        // P4: U = Gd[img] x E ; q = sum E .* U
        const char* Gd = smem + (wm * 4 + L) * 6144;
        f32x4 u[3][2];
#pragma unroll
        for (int m = 0; m < 3; ++m)
#pragma unroll
            for (int n = 0; n < 2; ++n) u[m][n] = (f32x4){0.f, 0.f, 0.f, 0.f};
#pragma unroll
        for (int ks = 0; ks < 2; ++ks) {
            int sz2 = (((ks * 4 + grp) ^ (lw & 7)) << 4);
            s16x8 ga[3], eb[2];
#pragma unroll
            for (int m = 0; m < 3; ++m)
                ga[m] = *(const s16x8*)(Gd + (m * 16 + lw) * 128 + sz2);
#pragma unroll
            for (int n = 0; n < 2; ++n) {
                int w = n * 16 + lw;
                eb[n] = *(const s16x8*)(myE + w * 128 + (((ks * 4 + grp) ^ (w & 7)) << 4));
            }
#pragma unroll
            for (int m = 0; m < 3; ++m)
#pragma unroll
                for (int n = 0; n < 2; ++n)
                    u[m][n] = __builtin_amdgcn_mfma_f32_16x16x32_bf16(ga[m], eb[n], u[m][n], 0, 0, 0);
        }
        float qq[2] = {0.f, 0.f};
#pragma unroll
        for (int m = 0; m < 3; ++m)
#pragma unroll
            for (int n = 0; n < 2; ++n) {
                int w = n * 16 + lw;
                const char* base = myE + w * 128;
#pragma unroll
                for (int rg = 0; rg < 4; rg += 2) {
                    int rp = m * 16 + grp * 4 + rg;
                    unsigned pv = *(const unsigned*)(base + (((rp >> 3) ^ (w & 7)) << 4) + (rp & 7) * 2);
                    qq[n] += u[m][n][rg] * bf2f(pv) + u[m][n][rg + 1] * bf2f(pv >> 16);
                }
            }
#pragma unroll
        for (int n = 0; n < 2; ++n) {
            qq[n] += __shfl_xor(qq[n], 16); qq[n] += __shfl_xor(qq[n], 32);
        }
        // P5: cosine sim + LSE over 32 words -> score
        float s0 = nm[0] / fmaxf(w1v[0] * sqrtf(fmaxf(qq[0], 0.f)), EPSF * dn[0]);
        float s1 = nm[1] / fmaxf(w1v[1] * sqrtf(fmaxf(qq[1], 0.f)), EPSF * dn[1]);
        float m2 = fmaxf(s0, s1);
        m2 = fmaxf(m2, __shfl_xor(m2, 1)); m2 = fmaxf(m2, __shfl_xor(m2, 2));
        m2 = fmaxf(m2, __shfl_xor(m2, 4)); m2 = fmaxf(m2, __shfl_xor(m2, 8));
        float ssum = __expf(LAM_LSE * (s0 - m2)) + __expf(LAM_LSE * (s1 - m2));
        ssum += __shfl_xor(ssum, 1); ssum += __shfl_xor(ssum, 2);
        ssum += __shfl_xor(ssum, 4); ssum += __shfl_xor(ssum, 8);
        if (l == 0)
            scores[(size_t)(jg * 8 + wm * 4 + L) * NI + ig * 4 + wn] =
                m2 + logf(ssum) / LAM_LSE;
    }
}

// ---- final hinge loss over the 128x128 score matrix ----
__global__ __launch_bounds__(256) void loss_kernel(const float* __restrict__ scores,
                                                   float* __restrict__ out) {
    __shared__ float diag[NJ];
    __shared__ float part[256];
    const int tid = threadIdx.x;
    if (tid < NJ) diag[tid] = scores[tid * NI + tid];
    __syncthreads();
    float m = 0.f;
    if (tid < 128) {
        const int a = tid;
        const float da = diag[a];
        for (int b = 0; b < NI; ++b) {
            if (b == a) continue;
            float c = MARGIN + scores[a * NI + b] - da;
            m = fmaxf(m, c);
        }
    } else {
        const int b = tid - 128;
        const float db = diag[b];
        for (int a = 0; a < NJ; ++a) {
            if (a == b) continue;
            float c = MARGIN + scores[a * NI + b] - db;
            m = fmaxf(m, c);
        }
    }
    part[tid] = m;
    __syncthreads();
    for (int st = 128; st > 0; st >>= 1) {
        if (tid < st) part[tid] += part[tid + st];
        __syncthreads();
    }
    if (tid == 0) out[0] = part[0];
}

extern "C" void kernel_launch(void* const* d_in, const int* in_sizes, int n_in,
                              void* d_out, int out_size, void* d_ws, size_t ws_size,
                              hipStream_t stream) {
    const float* im = (const float*)d_in[0];
    const float* s = (const float*)d_in[1];

    unsigned short* imsw = (unsigned short*)d_ws;
    unsigned short* ssw = imsw + IM_ELEMS;
    unsigned short* Gswp = ssw + S_ELEMS;
    float* w1 = (float*)(Gswp + GSW_ELEMS);
    float* scores = w1 + S_ROWS;

    hipFuncSetAttribute((const void*)pair8_kernel,
                        hipFuncAttributeMaxDynamicSharedMemorySize, SMEM_TOTAL);
    hipFuncSetAttribute((const void*)gram3_kernel,
                        hipFuncAttributeMaxDynamicSharedMemorySize, GRAM_SMEM);

    cvtswz2_kernel<<<dim3(ALL_ROWS / 2), dim3(256), 0, stream>>>(im, s, imsw, w1);
    gram3_kernel<<<dim3(NJ), dim3(256), GRAM_SMEM, stream>>>(imsw, Gswp);
    pair8_kernel<<<dim3(NI / 4, NJ / 8), dim3(512), SMEM_TOTAL, stream>>>(imsw, ssw, Gswp, w1, scores);
    loss_kernel<<<dim3(1), dim3(256), 0, stream>>>(scores, (float*)d_out);
}

// Round 14
// 117.559 us; speedup vs baseline: 1.5368x; 1.0413x over previous
//
#include <hip/hip_runtime.h>

#define NJ 128   // images
#define NI 128   // captions
#define NR 36    // regions
#define NW 32    // words
#define ND 1024  // feature dim

#define LAM_SM 9.0f
#define LAM_LSE 6.0f
#define MARGIN 0.2f
#define EPSF 1e-8f

typedef __attribute__((ext_vector_type(8))) short s16x8;
typedef __attribute__((ext_vector_type(4))) float f32x4;

#define IM_ROWS (NJ * NR)          // 4608
#define S_ROWS  (NI * NW)          // 4096
#define ALL_ROWS (IM_ROWS + S_ROWS)
#define IM_ELEMS (IM_ROWS * ND)
#define S_ELEMS  (S_ROWS * ND)
#define GSW_ELEMS (NJ * 48 * 64)   // bf16, swizzled, zero-padded
#define C_DW_PER_PAIR 768          // 3 mm3 x 2 nn x 128 dw(lane-pairs)

// pairG LDS (dynamic, 139264 B): buf = A 288x128B [0,36864) + B 256x128B -> 69632/buf
#define G_BOFF 36864
#define G_BUFSZ 69632
#define G_SMEM 139264
#define GRAM_SMEM 98304

__device__ __forceinline__ unsigned short f2bf(float x) {
    unsigned u = __float_as_uint(x);
    return (unsigned short)((u + 0x7FFFu + ((u >> 16) & 1u)) >> 16);
}
__device__ __forceinline__ unsigned pack2bf(float x, float y) {
    return (unsigned)f2bf(x) | ((unsigned)f2bf(y) << 16);
}
__device__ __forceinline__ float bf2f(unsigned v) {
    return __uint_as_float((v & 0xffffu) << 16);
}
__device__ __forceinline__ void gload16(const void* g, void* l) {
    __builtin_amdgcn_global_load_lds((const __attribute__((address_space(1))) unsigned int*)g,
                                     (__attribute__((address_space(3))) unsigned int*)l, 16, 0, 0);
}

// ---- merged f32->bf16 convert + 128B-window swizzle (key=row&7) + fused wnorm ----
__global__ __launch_bounds__(256) void cvtswz2_kernel(const float* __restrict__ im,
                                                      const float* __restrict__ s,
                                                      unsigned short* __restrict__ dst,
                                                      float* __restrict__ w1) {
    __shared__ float part[4];
    const int tid = threadIdx.x;
    int idx = blockIdx.x * 256 + tid;
    int row = idx >> 7, cw = idx & 127;
    int wd = cw >> 3, p = cw & 7;
    int sk = wd * 64 + ((p ^ (row & 7)) * 8);
    const float* srow = (row < IM_ROWS) ? (im + (size_t)row * ND)
                                        : (s + (size_t)(row - IM_ROWS) * ND);
    float4 v0 = *(const float4*)(srow + sk);
    float4 v1 = *(const float4*)(srow + sk + 4);
    ushort4 o0, o1;
    o0.x = f2bf(v0.x); o0.y = f2bf(v0.y); o0.z = f2bf(v0.z); o0.w = f2bf(v0.w);
    o1.x = f2bf(v1.x); o1.y = f2bf(v1.y); o1.z = f2bf(v1.z); o1.w = f2bf(v1.w);
    ((ushort4*)dst)[(size_t)idx * 2] = o0;
    ((ushort4*)dst)[(size_t)idx * 2 + 1] = o1;
    float ss = v0.x * v0.x + v0.y * v0.y + v0.z * v0.z + v0.w * v0.w +
               v1.x * v1.x + v1.y * v1.y + v1.z * v1.z + v1.w * v1.w;
    ss += __shfl_xor(ss, 1);  ss += __shfl_xor(ss, 2);  ss += __shfl_xor(ss, 4);
    ss += __shfl_xor(ss, 8);  ss += __shfl_xor(ss, 16); ss += __shfl_xor(ss, 32);
    if ((tid & 63) == 0) part[tid >> 6] = ss;
    __syncthreads();
    if ((tid & 127) == 0 && row >= IM_ROWS) {
        int h = tid >> 7;
        w1[row - IM_ROWS] = sqrtf(part[h * 2] + part[h * 2 + 1]);
    }
}

// ---- Gram via MFMA, 4-wave K-split (R10-proven) ----
__global__ __launch_bounds__(256) void gram3_kernel(const unsigned short* __restrict__ imsw,
                                                    unsigned short* __restrict__ Gsw) {
    extern __shared__ char gsm[];
    const int j = blockIdx.x;
    const int tid = threadIdx.x;
    const int wv = tid >> 6, l = tid & 63;
    const int grp = l >> 4, lw = l & 15;
    char* reg = gsm + wv * 24576;

#pragma unroll
    for (int u = 0; u < 6; ++u)
        *(int4*)(reg + 36 * 512 + (l + u * 64) * 16) = make_int4(0, 0, 0, 0);
    {
        const char* src = (const char*)imsw + ((size_t)j * 36 + (l >> 5)) * 2048 +
                          wv * 512 + (l & 31) * 16;
#pragma unroll
        for (int c = 0; c < 18; ++c)
            gload16(src + (size_t)c * 4096, reg + c * 1024);
    }
    asm volatile("s_waitcnt vmcnt(0)" ::: "memory");

    const int keyadj = (j & 1) * 4;
    f32x4 acc[3][3];
#pragma unroll
    for (int m = 0; m < 3; ++m)
#pragma unroll
        for (int n = 0; n < 3; ++n) acc[m][n] = (f32x4){0.f, 0.f, 0.f, 0.f};

#pragma unroll
    for (int ks = 0; ks < 8; ++ks) {
        const int widx = ks >> 1;
        const int swzg = ((((ks & 1) * 4 + grp) ^ ((lw + keyadj) & 7)) << 4);
        s16x8 fr[3];
#pragma unroll
        for (int m = 0; m < 3; ++m)
            fr[m] = *(const s16x8*)(reg + (m * 16 + lw) * 512 + widx * 128 + swzg);
#pragma unroll
        for (int m = 0; m < 3; ++m)
#pragma unroll
            for (int n = 0; n < 3; ++n)
                acc[m][n] = __builtin_amdgcn_mfma_f32_16x16x32_bf16(fr[m], fr[n], acc[m][n], 0, 0, 0);
    }
    __syncthreads();
    float* Gt = (float*)(gsm + wv * 9984);
#pragma unroll
    for (int m = 0; m < 3; ++m)
#pragma unroll
        for (int n = 0; n < 3; ++n)
#pragma unroll
            for (int r4 = 0; r4 < 4; ++r4)
                Gt[(m * 16 + grp * 4 + r4) * 52 + n * 16 + lw] = acc[m][n][r4];
    __syncthreads();
    const float* G0 = (const float*)gsm;
    const float* G1 = (const float*)(gsm + 9984);
    const float* G2 = (const float*)(gsm + 19968);
    const float* G3 = (const float*)(gsm + 29952);
#pragma unroll
    for (int u = 0; u < 2; ++u) {
        int e = tid + u * 256;
        if (e < 384) {
            int row = e >> 3, p = e & 7;
            int k0 = (p ^ (row & 7)) * 8;
            float v[8];
#pragma unroll
            for (int i = 0; i < 8; ++i) {
                int k = k0 + i;
                v[i] = (k < 48) ? (G0[row * 52 + k] + G1[row * 52 + k] +
                                   G2[row * 52 + k] + G3[row * 52 + k]) : 0.f;
            }
            ushort4 o0, o1;
            o0.x = f2bf(v[0]); o0.y = f2bf(v[1]); o0.z = f2bf(v[2]); o0.w = f2bf(v[3]);
            o1.x = f2bf(v[4]); o1.y = f2bf(v[5]); o1.z = f2bf(v[6]); o1.w = f2bf(v[7]);
            ushort4* dp = (ushort4*)((char*)Gsw + (size_t)j * 6144 + row * 128 + p * 16);
            dp[0] = o0; dp[1] = o1;
        }
    }
}

// ---- pairG: PURE GEMM. 8 img x 8 cap, 8 waves (2M x 4N), acc[9][4]=144 AGPR ----
// No epilogue -> loop arch-VGPR demand ~70, so 144 AGPR + VGPR fits the 2-wave/EU
// 256-reg unified budget (R3-R7's spill was the epilogue's extra VGPR pressure).
// One generation (256 blocks), A-frag reused by 4 MFMA. C dumped as bf16 pairs.
__global__ __attribute__((amdgpu_flat_work_group_size(512, 512)))
__attribute__((amdgpu_waves_per_eu(2, 2)))
void pairG_kernel(const unsigned short* __restrict__ imsw,
                  const unsigned short* __restrict__ ssw,
                  unsigned* __restrict__ C) {
    extern __shared__ char smem[];
    const int ig = blockIdx.x;   // caption octet
    const int jg = blockIdx.y;   // image octet
    const int tid = threadIdx.x;
    const int l = tid & 63, wv = tid >> 6;
    const int grp = l >> 4, lw = l & 15;
    const int wm = wv >> 2, wn = wv & 3;

    const char* aSrc = (const char*)imsw + ((size_t)(jg * 288) + (l >> 3)) * 2048 + (l & 7) * 16;
    const char* bSrc = (const char*)ssw + ((size_t)(ig * 256) + (l >> 3)) * 2048 + (l & 7) * 16;

    f32x4 acc[9][4];
#pragma unroll
    for (int m = 0; m < 9; ++m)
#pragma unroll
        for (int n = 0; n < 4; ++n) acc[m][n] = (f32x4){0.f, 0.f, 0.f, 0.f};

    auto stage = [&](int bb, int k0b) {
        char* ab = smem + bb;
#pragma unroll
        for (int t = 0; t < 5; ++t) {
            int ii = wv + 8 * t;
            if (ii < 36) gload16(aSrc + (size_t)ii * 16384 + k0b, ab + ii * 1024);
        }
        char* bbp = smem + bb + G_BOFF;
#pragma unroll
        for (int t = 0; t < 4; ++t) {
            int ii = wv + 8 * t;
            gload16(bSrc + (size_t)ii * 16384 + k0b, bbp + ii * 1024);
        }
    };
    auto compute = [&](int bb) {
        const char* A = smem + bb;
        const char* B = smem + bb + G_BOFF;
#pragma unroll
        for (int ks = 0; ks < 2; ++ks) {
            const int swz = (((ks * 4 + grp) ^ (lw & 7)) << 4);
            s16x8 bf[4];
#pragma unroll
            for (int n = 0; n < 4; ++n)
                bf[n] = *(const s16x8*)(B + (wn * 64 + n * 16 + lw) * 128 + swz);
#pragma unroll
            for (int m = 0; m < 9; ++m) {
                s16x8 a = *(const s16x8*)(A + (wm * 144 + m * 16 + lw) * 128 + swz);
#pragma unroll
                for (int n = 0; n < 4; ++n)
                    acc[m][n] = __builtin_amdgcn_mfma_f32_16x16x32_bf16(a, bf[n], acc[m][n], 0, 0, 0);
            }
        }
    };

    stage(0, 0);
    asm volatile("s_waitcnt vmcnt(0)" ::: "memory");
    __syncthreads();
    for (int t = 0; t < 16; ++t) {
        if (t < 15) stage(((t + 1) & 1) * G_BUFSZ, (t + 1) * 128);
        compute((t & 1) * G_BUFSZ);
        asm volatile("s_waitcnt vmcnt(0)" ::: "memory");
        __syncthreads();
    }

    // C-store: bf16 pairs, fully coalesced dwordx2 per (L, mm3, n)
#pragma unroll
    for (int L = 0; L < 4; ++L)
#pragma unroll
        for (int mm3 = 0; mm3 < 3; ++mm3) {
            const int m = 2 * L + mm3;
#pragma unroll
            for (int n = 0; n < 4; ++n) {
                const int p = (jg * 8 + wm * 4 + L) * NI + ig * 8 + wn * 2 + (n >> 1);
                const int nn = n & 1;
                size_t idx = ((size_t)(p * 3 + mm3) * 2 + nn) * 128 + l * 2;
                uint2 v;
                v.x = pack2bf(acc[m][n][0], acc[m][n][1]);
                v.y = pack2bf(acc[m][n][2], acc[m][n][3]);
                *(uint2*)(C + idx) = v;
            }
        }
}

// ---- pairE: epilogue, 1 wave = 1 pair; block = 1 image x 8 captions ----
// LDS: Gd 6144 [0,6144) | E 8x4096 [6144,38912). Norms in registers.
__global__ __launch_bounds__(512) void pairE_kernel(const unsigned* __restrict__ C,
                                                    const unsigned short* __restrict__ Gswp,
                                                    const float* __restrict__ w1g,
                                                    float* __restrict__ scores) {
    __shared__ __align__(16) char smem[38912];
    const int ib = blockIdx.x;   // caption octet
    const int j = blockIdx.y;    // image
    const int tid = threadIdx.x;
    const int l = tid & 63, wv = tid >> 6;
    const int grp = l >> 4, lw = l & 15;
    const int i = ib * 8 + wv;
    const int p = j * NI + i;
    const int L = j & 3;         // image's slot within its G-wave (j = jg*8+wm*4+L)
    char* const Gd = smem;
    char* const myE = smem + 6144 + wv * 4096;

    // block-wide Gd load (image j's 48x64 swizzled Gram)
    if (tid < 384)
        *(int4*)(Gd + tid * 16) = *(const int4*)((const char*)Gswp + (size_t)j * 6144 + tid * 16);

    // my 12 dwords of C
    uint2 cv[3][2];
#pragma unroll
    for (int mm3 = 0; mm3 < 3; ++mm3)
#pragma unroll
        for (int nn = 0; nn < 2; ++nn)
            cv[mm3][nn] = *(const uint2*)(C + ((size_t)(p * 3 + mm3) * 2 + nn) * 128 + l * 2);

    // zero E pads (regions 36..63)
#pragma unroll
    for (int u = 0; u < 7; ++u) {
        int e = l + u * 64;
        int w = e / 14, pr = e - w * 14 + 18;
        *(unsigned*)(myE + w * 128 + (((pr >> 2) ^ (w & 7)) << 4) + (pr & 3) * 4) = 0u;
    }

    // unpack helper: a(mm3, nn, reg)
#define AV(mm3, nn, reg) ((reg) == 0 ? bf2f(cv[mm3][nn].x) : (reg) == 1 ? bf2f(cv[mm3][nn].x >> 16) \
                          : (reg) == 2 ? bf2f(cv[mm3][nn].y) : bf2f(cv[mm3][nn].y >> 16))

    // P1: inverse region norms, in registers (all lanes get the reduced value)
    float inv[3][4];
#pragma unroll
    for (int mm3 = 0; mm3 < 3; ++mm3)
#pragma unroll
        for (int reg = 0; reg < 4; ++reg) {
            float a0 = AV(mm3, 0, reg), a1 = AV(mm3, 1, reg);
            float l0 = a0 > 0.f ? a0 : 0.1f * a0;
            float l1 = a1 > 0.f ? a1 : 0.1f * a1;
            float ss = l0 * l0 + l1 * l1;
            ss += __shfl_xor(ss, 1); ss += __shfl_xor(ss, 2);
            ss += __shfl_xor(ss, 4); ss += __shfl_xor(ss, 8);
            inv[mm3][reg] = 1.f / (sqrtf(ss) + EPSF);
        }

    // P2: per-word max logit (valid rows only)
    float mx[2] = {-1e30f, -1e30f};
#pragma unroll
    for (int mm3 = 0; mm3 < 3; ++mm3) {
        int rbase = (2 * L + mm3) * 16 + grp * 4;
        bool pred = ((rbase * 1821) >> 16) == L;
#pragma unroll
        for (int nn = 0; nn < 2; ++nn) {
            float t4 = -1e30f;
#pragma unroll
            for (int reg = 0; reg < 4; ++reg) {
                float a = AV(mm3, nn, reg);
                float lk = a > 0.f ? a : 0.1f * a;
                t4 = fmaxf(t4, LAM_SM * lk * inv[mm3][reg]);
            }
            mx[nn] = pred ? fmaxf(mx[nn], t4) : mx[nn];
        }
    }
#pragma unroll
    for (int nn = 0; nn < 2; ++nn) {
        mx[nn] = fmaxf(mx[nn], __shfl_xor(mx[nn], 16));
        mx[nn] = fmaxf(mx[nn], __shfl_xor(mx[nn], 32));
    }

    // P3: exp, den/num, E-write
    float dn[2] = {0.f, 0.f}, nm[2] = {0.f, 0.f};
#pragma unroll
    for (int mm3 = 0; mm3 < 3; ++mm3) {
        int rbase = (2 * L + mm3) * 16 + grp * 4;
        bool pred = ((rbase * 1821) >> 16) == L;
        int rl0 = rbase - 36 * L;
#pragma unroll
        for (int nn = 0; nn < 2; ++nn) {
            int w = nn * 16 + lw;
            float e[4];
#pragma unroll
            for (int reg = 0; reg < 4; ++reg) {
                float a = AV(mm3, nn, reg);
                float lk = a > 0.f ? a : 0.1f * a;
                float tl = LAM_SM * lk * inv[mm3][reg];
                e[reg] = pred ? __expf(tl - mx[nn]) : 0.f;
                dn[nn] += e[reg];
                nm[nn] += e[reg] * a;
            }
            if (pred) {
                char* base = myE + w * 128 + (((rl0 >> 3) ^ (w & 7)) << 4) + (rl0 & 7) * 2;
                *(unsigned*)(base) = pack2bf(e[0], e[1]);
                *(unsigned*)(base + 4) = pack2bf(e[2], e[3]);
            }
        }
    }
#pragma unroll
    for (int nn = 0; nn < 2; ++nn) {
        dn[nn] += __shfl_xor(dn[nn], 16); dn[nn] += __shfl_xor(dn[nn], 32);
        nm[nn] += __shfl_xor(nm[nn], 16); nm[nn] += __shfl_xor(nm[nn], 32);
    }
    __syncthreads();   // Gd visible to all waves; own E-writes ordered by lgkm deps

    // P4: U = Gd x E ; q = sum E .* U
    f32x4 u[3][2];
#pragma unroll
    for (int m = 0; m < 3; ++m)
#pragma unroll
        for (int nn = 0; nn < 2; ++nn) u[m][nn] = (f32x4){0.f, 0.f, 0.f, 0.f};
#pragma unroll
    for (int ks = 0; ks < 2; ++ks) {
        int sz2 = (((ks * 4 + grp) ^ (lw & 7)) << 4);
        s16x8 ga[3], eb[2];
#pragma unroll
        for (int m = 0; m < 3; ++m)
            ga[m] = *(const s16x8*)(Gd + (m * 16 + lw) * 128 + sz2);
#pragma unroll
        for (int nn = 0; nn < 2; ++nn) {
            int w = nn * 16 + lw;
            eb[nn] = *(const s16x8*)(myE + w * 128 + (((ks * 4 + grp) ^ (w & 7)) << 4));
        }
#pragma unroll
        for (int m = 0; m < 3; ++m)
#pragma unroll
            for (int nn = 0; nn < 2; ++nn)
                u[m][nn] = __builtin_amdgcn_mfma_f32_16x16x32_bf16(ga[m], eb[nn], u[m][nn], 0, 0, 0);
    }
    float qq[2] = {0.f, 0.f};
#pragma unroll
    for (int m = 0; m < 3; ++m)
#pragma unroll
        for (int nn = 0; nn < 2; ++nn) {
            int w = nn * 16 + lw;
            const char* base = myE + w * 128;
#pragma unroll
            for (int rg = 0; rg < 4; rg += 2) {
                int rp = m * 16 + grp * 4 + rg;
                unsigned pv = *(const unsigned*)(base + (((rp >> 3) ^ (w & 7)) << 4) + (rp & 7) * 2);
                qq[nn] += u[m][nn][rg] * bf2f(pv) + u[m][nn][rg + 1] * bf2f(pv >> 16);
            }
        }
#pragma unroll
    for (int nn = 0; nn < 2; ++nn) {
        qq[nn] += __shfl_xor(qq[nn], 16); qq[nn] += __shfl_xor(qq[nn], 32);
    }
    // P5: cosine sim + LSE over 32 words -> score
    float w1a = w1g[i * 32 + lw], w1b = w1g[i * 32 + 16 + lw];
    float s0 = nm[0] / fmaxf(w1a * sqrtf(fmaxf(qq[0], 0.f)), EPSF * dn[0]);
    float s1 = nm[1] / fmaxf(w1b * sqrtf(fmaxf(qq[1], 0.f)), EPSF * dn[1]);
    float m2 = fmaxf(s0, s1);
    m2 = fmaxf(m2, __shfl_xor(m2, 1)); m2 = fmaxf(m2, __shfl_xor(m2, 2));
    m2 = fmaxf(m2, __shfl_xor(m2, 4)); m2 = fmaxf(m2, __shfl_xor(m2, 8));
    float ssum = __expf(LAM_LSE * (s0 - m2)) + __expf(LAM_LSE * (s1 - m2));
    ssum += __shfl_xor(ssum, 1); ssum += __shfl_xor(ssum, 2);
    ssum += __shfl_xor(ssum, 4); ssum += __shfl_xor(ssum, 8);
    if (l == 0) scores[p] = m2 + logf(ssum) / LAM_LSE;
#undef AV
}

// ---- final hinge loss over the 128x128 score matrix ----
__global__ __launch_bounds__(256) void loss_kernel(const float* __restrict__ scores,
                                                   float* __restrict__ out) {
    __shared__ float diag[NJ];
    __shared__ float part[256];
    const int tid = threadIdx.x;
    if (tid < NJ) diag[tid] = scores[tid * NI + tid];
    __syncthreads();
    float m = 0.f;
    if (tid < 128) {
        const int a = tid;
        const float da = diag[a];
        for (int b = 0; b < NI; ++b) {
            if (b == a) continue;
            float c = MARGIN + scores[a * NI + b] - da;
            m = fmaxf(m, c);
        }
    } else {
        const int b = tid - 128;
        const float db = diag[b];
        for (int a = 0; a < NJ; ++a) {
            if (a == b) continue;
            float c = MARGIN + scores[a * NI + b] - db;
            m = fmaxf(m, c);
        }
    }
    part[tid] = m;
    __syncthreads();
    for (int st = 128; st > 0; st >>= 1) {
        if (tid < st) part[tid] += part[tid + st];
        __syncthreads();
    }
    if (tid == 0) out[0] = part[0];
}

extern "C" void kernel_launch(void* const* d_in, const int* in_sizes, int n_in,
                              void* d_out, int out_size, void* d_ws, size_t ws_size,
                              hipStream_t stream) {
    const float* im = (const float*)d_in[0];
    const float* s = (const float*)d_in[1];

    unsigned short* imsw = (unsigned short*)d_ws;
    unsigned short* ssw = imsw + IM_ELEMS;
    unsigned short* Gswp = ssw + S_ELEMS;
    float* w1 = (float*)(Gswp + GSW_ELEMS);
    float* scores = w1 + S_ROWS;
    unsigned* C = (unsigned*)(scores + NJ * NI);

    hipFuncSetAttribute((const void*)pairG_kernel,
                        hipFuncAttributeMaxDynamicSharedMemorySize, G_SMEM);
    hipFuncSetAttribute((const void*)gram3_kernel,
                        hipFuncAttributeMaxDynamicSharedMemorySize, GRAM_SMEM);

    cvtswz2_kernel<<<dim3(ALL_ROWS / 2), dim3(256), 0, stream>>>(im, s, imsw, w1);
    gram3_kernel<<<dim3(NJ), dim3(256), GRAM_SMEM, stream>>>(imsw, Gswp);
    pairG_kernel<<<dim3(NI / 8, NJ / 8), dim3(512), G_SMEM, stream>>>(imsw, ssw, C);
    pairE_kernel<<<dim3(NI / 8, NJ), dim3(512), 0, stream>>>(C, Gswp, w1, scores);
    loss_kernel<<<dim3(1), dim3(256), 0, stream>>>(scores, (float*)d_out);
}

// Round 15
// 99.056 us; speedup vs baseline: 1.8239x; 1.1868x over previous
//
#include <hip/hip_runtime.h>

#define NJ 128   // images
#define NI 128   // captions
#define NR 36    // regions
#define NW 32    // words
#define ND 1024  // feature dim

#define LAM_SM 9.0f
#define LAM_LSE 6.0f
#define MARGIN 0.2f
#define EPSF 1e-8f

typedef __attribute__((ext_vector_type(8))) short s16x8;
typedef __attribute__((ext_vector_type(4))) float f32x4;

#define IM_ROWS (NJ * NR)          // 4608
#define S_ROWS  (NI * NW)          // 4096
#define ALL_ROWS (IM_ROWS + S_ROWS)
#define IM_ELEMS (IM_ROWS * ND)
#define S_ELEMS  (S_ROWS * ND)
#define GSW_ELEMS (NJ * 48 * 64)   // bf16, swizzled, zero-padded

// pairG LDS (dynamic, 139264 B): buf = A 288x128B [0,36864) + B 256x128B -> 69632/buf
#define G_BOFF 36864
#define G_BUFSZ 69632
#define G_SMEM 139264
#define GRAM_SMEM 98304            // gram4: 8 waves x 12288 staging; reduce overlay 8x9984

__device__ __forceinline__ unsigned short f2bf(float x) {
    unsigned u = __float_as_uint(x);
    return (unsigned short)((u + 0x7FFFu + ((u >> 16) & 1u)) >> 16);
}
__device__ __forceinline__ unsigned pack2bf(float x, float y) {
    return (unsigned)f2bf(x) | ((unsigned)f2bf(y) << 16);
}
__device__ __forceinline__ float bf2f(unsigned v) {
    return __uint_as_float((v & 0xffffu) << 16);
}
__device__ __forceinline__ void gload16(const void* g, void* l) {
    __builtin_amdgcn_global_load_lds((const __attribute__((address_space(1))) unsigned int*)g,
                                     (__attribute__((address_space(3))) unsigned int*)l, 16, 0, 0);
}

// ---- merged f32->bf16 convert + 128B-window swizzle (key=row&7) + fused wnorm ----
__global__ __launch_bounds__(256) void cvtswz2_kernel(const float* __restrict__ im,
                                                      const float* __restrict__ s,
                                                      unsigned short* __restrict__ dst,
                                                      float* __restrict__ w1) {
    __shared__ float part[4];
    const int tid = threadIdx.x;
    int idx = blockIdx.x * 256 + tid;
    int row = idx >> 7, cw = idx & 127;
    int wd = cw >> 3, p = cw & 7;
    int sk = wd * 64 + ((p ^ (row & 7)) * 8);
    const float* srow = (row < IM_ROWS) ? (im + (size_t)row * ND)
                                        : (s + (size_t)(row - IM_ROWS) * ND);
    float4 v0 = *(const float4*)(srow + sk);
    float4 v1 = *(const float4*)(srow + sk + 4);
    ushort4 o0, o1;
    o0.x = f2bf(v0.x); o0.y = f2bf(v0.y); o0.z = f2bf(v0.z); o0.w = f2bf(v0.w);
    o1.x = f2bf(v1.x); o1.y = f2bf(v1.y); o1.z = f2bf(v1.z); o1.w = f2bf(v1.w);
    ((ushort4*)dst)[(size_t)idx * 2] = o0;
    ((ushort4*)dst)[(size_t)idx * 2 + 1] = o1;
    float ss = v0.x * v0.x + v0.y * v0.y + v0.z * v0.z + v0.w * v0.w +
               v1.x * v1.x + v1.y * v1.y + v1.z * v1.z + v1.w * v1.w;
    ss += __shfl_xor(ss, 1);  ss += __shfl_xor(ss, 2);  ss += __shfl_xor(ss, 4);
    ss += __shfl_xor(ss, 8);  ss += __shfl_xor(ss, 16); ss += __shfl_xor(ss, 32);
    if ((tid & 63) == 0) part[tid >> 6] = ss;
    __syncthreads();
    if ((tid & 127) == 0 && row >= IM_ROWS) {
        int h = tid >> 7;
        w1[row - IM_ROWS] = sqrtf(part[h * 2] + part[h * 2 + 1]);
    }
}

// ---- Gram via MFMA, 8-wave K-eighth split (2x TLP vs R10's gram3) ----
// Gsw[j] = bf16 swizzled 48x64 (rows/cols >=36 zero), 128B rows, key=row&7.
__global__ __launch_bounds__(512) void gram4_kernel(const unsigned short* __restrict__ imsw,
                                                    unsigned short* __restrict__ Gsw) {
    extern __shared__ char gsm[];
    const int j = blockIdx.x;
    const int tid = threadIdx.x;
    const int wv = tid >> 6, l = tid & 63;
    const int grp = l >> 4, lw = l & 15;
    char* reg = gsm + wv * 12288;   // own K-eighth: 48 rows x 256B

    // zero pad rows 36..47 (12 x 256B = 192 chunks of 16B)
#pragma unroll
    for (int u = 0; u < 3; ++u)
        *(int4*)(reg + 36 * 256 + (l + u * 64) * 16) = make_int4(0, 0, 0, 0);
    // stage 36 rows x 256B (K-eighth wv): 9 chunks of 1KB (4 rows each)
    {
        const char* src = (const char*)imsw + ((size_t)j * 36 + (l >> 4)) * 2048 +
                          wv * 256 + (l & 15) * 16;
#pragma unroll
        for (int c = 0; c < 9; ++c)
            gload16(src + (size_t)c * 4 * 2048, reg + c * 1024);
    }
    asm volatile("s_waitcnt vmcnt(0)" ::: "memory");

    const int keyadj = (j & 1) * 4;   // (j*36)&7 == 4*(j&1)
    f32x4 acc[3][3];
#pragma unroll
    for (int m = 0; m < 3; ++m)
#pragma unroll
        for (int n = 0; n < 3; ++n) acc[m][n] = (f32x4){0.f, 0.f, 0.f, 0.f};

#pragma unroll
    for (int ks = 0; ks < 4; ++ks) {
        s16x8 fr[3];
#pragma unroll
        for (int m = 0; m < 3; ++m) {
            int r = m * 16 + lw;
            int swzg = ((((ks & 1) * 4 + grp) ^ ((r + keyadj) & 7)) << 4);
            fr[m] = *(const s16x8*)(reg + r * 256 + (ks >> 1) * 128 + swzg);
        }
#pragma unroll
        for (int m = 0; m < 3; ++m)
#pragma unroll
            for (int n = 0; n < 3; ++n)
                acc[m][n] = __builtin_amdgcn_mfma_f32_16x16x32_bf16(fr[m], fr[n], acc[m][n], 0, 0, 0);
    }
    __syncthreads();   // all waves' ds_reads done; staging overlay becomes partials
    float* Gt = (float*)(gsm + wv * 9984);
#pragma unroll
    for (int m = 0; m < 3; ++m)
#pragma unroll
        for (int n = 0; n < 3; ++n)
#pragma unroll
            for (int r4 = 0; r4 < 4; ++r4)
                Gt[(m * 16 + grp * 4 + r4) * 52 + n * 16 + lw] = acc[m][n][r4];
    __syncthreads();
    // reduce 8 partials + pack bf16 swizzled (key=row&7, 128B rows)
    if (tid < 384) {
        int row = tid >> 3, p = tid & 7;
        int k0 = (p ^ (row & 7)) * 8;
        float v[8];
#pragma unroll
        for (int i = 0; i < 8; ++i) {
            int k = k0 + i;
            float sum = 0.f;
            if (k < 48) {
#pragma unroll
                for (int w8 = 0; w8 < 8; ++w8)
                    sum += ((const float*)(gsm + w8 * 9984))[row * 52 + k];
            }
            v[i] = sum;
        }
        ushort4 o0, o1;
        o0.x = f2bf(v[0]); o0.y = f2bf(v[1]); o0.z = f2bf(v[2]); o0.w = f2bf(v[3]);
        o1.x = f2bf(v[4]); o1.y = f2bf(v[5]); o1.z = f2bf(v[6]); o1.w = f2bf(v[7]);
        ushort4* dp = (ushort4*)((char*)Gsw + (size_t)j * 6144 + row * 128 + p * 16);
        dp[0] = o0; dp[1] = o1;
    }
}

// ---- pairG: PURE GEMM (R14-proven, 41us / ~944 TF). 8 img x 8 cap, acc[9][4] ----
__global__ __attribute__((amdgpu_flat_work_group_size(512, 512)))
__attribute__((amdgpu_waves_per_eu(2, 2)))
void pairG_kernel(const unsigned short* __restrict__ imsw,
                  const unsigned short* __restrict__ ssw,
                  unsigned* __restrict__ C) {
    extern __shared__ char smem[];
    const int ig = blockIdx.x;   // caption octet
    const int jg = blockIdx.y;   // image octet
    const int tid = threadIdx.x;
    const int l = tid & 63, wv = tid >> 6;
    const int grp = l >> 4, lw = l & 15;
    const int wm = wv >> 2, wn = wv & 3;

    const char* aSrc = (const char*)imsw + ((size_t)(jg * 288) + (l >> 3)) * 2048 + (l & 7) * 16;
    const char* bSrc = (const char*)ssw + ((size_t)(ig * 256) + (l >> 3)) * 2048 + (l & 7) * 16;

    f32x4 acc[9][4];
#pragma unroll
    for (int m = 0; m < 9; ++m)
#pragma unroll
        for (int n = 0; n < 4; ++n) acc[m][n] = (f32x4){0.f, 0.f, 0.f, 0.f};

    auto stage = [&](int bb, int k0b) {
        char* ab = smem + bb;
#pragma unroll
        for (int t = 0; t < 5; ++t) {
            int ii = wv + 8 * t;
            if (ii < 36) gload16(aSrc + (size_t)ii * 16384 + k0b, ab + ii * 1024);
        }
        char* bbp = smem + bb + G_BOFF;
#pragma unroll
        for (int t = 0; t < 4; ++t) {
            int ii = wv + 8 * t;
            gload16(bSrc + (size_t)ii * 16384 + k0b, bbp + ii * 1024);
        }
    };
    auto compute = [&](int bb) {
        const char* A = smem + bb;
        const char* B = smem + bb + G_BOFF;
#pragma unroll
        for (int ks = 0; ks < 2; ++ks) {
            const int swz = (((ks * 4 + grp) ^ (lw & 7)) << 4);
            s16x8 bf[4];
#pragma unroll
            for (int n = 0; n < 4; ++n)
                bf[n] = *(const s16x8*)(B + (wn * 64 + n * 16 + lw) * 128 + swz);
#pragma unroll
            for (int m = 0; m < 9; ++m) {
                s16x8 a = *(const s16x8*)(A + (wm * 144 + m * 16 + lw) * 128 + swz);
#pragma unroll
                for (int n = 0; n < 4; ++n)
                    acc[m][n] = __builtin_amdgcn_mfma_f32_16x16x32_bf16(a, bf[n], acc[m][n], 0, 0, 0);
            }
        }
    };

    stage(0, 0);
    asm volatile("s_waitcnt vmcnt(0)" ::: "memory");
    __syncthreads();
    for (int t = 0; t < 16; ++t) {
        if (t < 15) stage(((t + 1) & 1) * G_BUFSZ, (t + 1) * 128);
        compute((t & 1) * G_BUFSZ);
        asm volatile("s_waitcnt vmcnt(0)" ::: "memory");
        __syncthreads();
    }

    // C-store: bf16 pairs, fully coalesced dwordx2 per (L, mm3, n)
#pragma unroll
    for (int L = 0; L < 4; ++L)
#pragma unroll
        for (int mm3 = 0; mm3 < 3; ++mm3) {
            const int m = 2 * L + mm3;
#pragma unroll
            for (int n = 0; n < 4; ++n) {
                const int p = (jg * 8 + wm * 4 + L) * NI + ig * 8 + wn * 2 + (n >> 1);
                const int nn = n & 1;
                size_t idx = ((size_t)(p * 3 + mm3) * 2 + nn) * 128 + l * 2;
                uint2 v;
                v.x = pack2bf(acc[m][n][0], acc[m][n][1]);
                v.y = pack2bf(acc[m][n][2], acc[m][n][3]);
                *(uint2*)(C + idx) = v;
            }
        }
}

// ---- pairE: epilogue, 1 wave = 1 pair; block = 1 image x 8 captions (R14-proven) ----
__global__ __launch_bounds__(512) void pairE_kernel(const unsigned* __restrict__ C,
                                                    const unsigned short* __restrict__ Gswp,
                                                    const float* __restrict__ w1g,
                                                    float* __restrict__ scores) {
    __shared__ __align__(16) char smem[38912];
    const int ib = blockIdx.x;   // caption octet
    const int j = blockIdx.y;    // image
    const int tid = threadIdx.x;
    const int l = tid & 63, wv = tid >> 6;
    const int grp = l >> 4, lw = l & 15;
    const int i = ib * 8 + wv;
    const int p = j * NI + i;
    const int L = j & 3;
    char* const Gd = smem;
    char* const myE = smem + 6144 + wv * 4096;

    if (tid < 384)
        *(int4*)(Gd + tid * 16) = *(const int4*)((const char*)Gswp + (size_t)j * 6144 + tid * 16);

    uint2 cv[3][2];
#pragma unroll
    for (int mm3 = 0; mm3 < 3; ++mm3)
#pragma unroll
        for (int nn = 0; nn < 2; ++nn)
            cv[mm3][nn] = *(const uint2*)(C + ((size_t)(p * 3 + mm3) * 2 + nn) * 128 + l * 2);

#pragma unroll
    for (int u = 0; u < 7; ++u) {
        int e = l + u * 64;
        int w = e / 14, pr = e - w * 14 + 18;
        *(unsigned*)(myE + w * 128 + (((pr >> 2) ^ (w & 7)) << 4) + (pr & 3) * 4) = 0u;
    }

#define AV(mm3, nn, reg) ((reg) == 0 ? bf2f(cv[mm3][nn].x) : (reg) == 1 ? bf2f(cv[mm3][nn].x >> 16) \
                          : (reg) == 2 ? bf2f(cv[mm3][nn].y) : bf2f(cv[mm3][nn].y >> 16))

    float inv[3][4];
#pragma unroll
    for (int mm3 = 0; mm3 < 3; ++mm3)
#pragma unroll
        for (int reg = 0; reg < 4; ++reg) {
            float a0 = AV(mm3, 0, reg), a1 = AV(mm3, 1, reg);
            float l0 = a0 > 0.f ? a0 : 0.1f * a0;
            float l1 = a1 > 0.f ? a1 : 0.1f * a1;
            float ss = l0 * l0 + l1 * l1;
            ss += __shfl_xor(ss, 1); ss += __shfl_xor(ss, 2);
            ss += __shfl_xor(ss, 4); ss += __shfl_xor(ss, 8);
            inv[mm3][reg] = 1.f / (sqrtf(ss) + EPSF);
        }

    float mx[2] = {-1e30f, -1e30f};
#pragma unroll
    for (int mm3 = 0; mm3 < 3; ++mm3) {
        int rbase = (2 * L + mm3) * 16 + grp * 4;
        bool pred = ((rbase * 1821) >> 16) == L;
#pragma unroll
        for (int nn = 0; nn < 2; ++nn) {
            float t4 = -1e30f;
#pragma unroll
            for (int reg = 0; reg < 4; ++reg) {
                float a = AV(mm3, nn, reg);
                float lk = a > 0.f ? a : 0.1f * a;
                t4 = fmaxf(t4, LAM_SM * lk * inv[mm3][reg]);
            }
            mx[nn] = pred ? fmaxf(mx[nn], t4) : mx[nn];
        }
    }
#pragma unroll
    for (int nn = 0; nn < 2; ++nn) {
        mx[nn] = fmaxf(mx[nn], __shfl_xor(mx[nn], 16));
        mx[nn] = fmaxf(mx[nn], __shfl_xor(mx[nn], 32));
    }

    float dn[2] = {0.f, 0.f}, nm[2] = {0.f, 0.f};
#pragma unroll
    for (int mm3 = 0; mm3 < 3; ++mm3) {
        int rbase = (2 * L + mm3) * 16 + grp * 4;
        bool pred = ((rbase * 1821) >> 16) == L;
        int rl0 = rbase - 36 * L;
#pragma unroll
        for (int nn = 0; nn < 2; ++nn) {
            int w = nn * 16 + lw;
            float e[4];
#pragma unroll
            for (int reg = 0; reg < 4; ++reg) {
                float a = AV(mm3, nn, reg);
                float lk = a > 0.f ? a : 0.1f * a;
                float tl = LAM_SM * lk * inv[mm3][reg];
                e[reg] = pred ? __expf(tl - mx[nn]) : 0.f;
                dn[nn] += e[reg];
                nm[nn] += e[reg] * a;
            }
            if (pred) {
                char* base = myE + w * 128 + (((rl0 >> 3) ^ (w & 7)) << 4) + (rl0 & 7) * 2;
                *(unsigned*)(base) = pack2bf(e[0], e[1]);
                *(unsigned*)(base + 4) = pack2bf(e[2], e[3]);
            }
        }
    }
#pragma unroll
    for (int nn = 0; nn < 2; ++nn) {
        dn[nn] += __shfl_xor(dn[nn], 16); dn[nn] += __shfl_xor(dn[nn], 32);
        nm[nn] += __shfl_xor(nm[nn], 16); nm[nn] += __shfl_xor(nm[nn], 32);
    }
    __syncthreads();

    f32x4 u[3][2];
#pragma unroll
    for (int m = 0; m < 3; ++m)
#pragma unroll
        for (int nn = 0; nn < 2; ++nn) u[m][nn] = (f32x4){0.f, 0.f, 0.f, 0.f};
#pragma unroll
    for (int ks = 0; ks < 2; ++ks) {
        int sz2 = (((ks * 4 + grp) ^ (lw & 7)) << 4);
        s16x8 ga[3], eb[2];
#pragma unroll
        for (int m = 0; m < 3; ++m)
            ga[m] = *(const s16x8*)(Gd + (m * 16 + lw) * 128 + sz2);
#pragma unroll
        for (int nn = 0; nn < 2; ++nn) {
            int w = nn * 16 + lw;
            eb[nn] = *(const s16x8*)(myE + w * 128 + (((ks * 4 + grp) ^ (w & 7)) << 4));
        }
#pragma unroll
        for (int m = 0; m < 3; ++m)
#pragma unroll
            for (int nn = 0; nn < 2; ++nn)
                u[m][nn] = __builtin_amdgcn_mfma_f32_16x16x32_bf16(ga[m], eb[nn], u[m][nn], 0, 0, 0);
    }
    float qq[2] = {0.f, 0.f};
#pragma unroll
    for (int m = 0; m < 3; ++m)
#pragma unroll
        for (int nn = 0; nn < 2; ++nn) {
            int w = nn * 16 + lw;
            const char* base = myE + w * 128;
#pragma unroll
            for (int rg = 0; rg < 4; rg += 2) {
                int rp = m * 16 + grp * 4 + rg;
                unsigned pv = *(const unsigned*)(base + (((rp >> 3) ^ (w & 7)) << 4) + (rp & 7) * 2);
                qq[nn] += u[m][nn][rg] * bf2f(pv) + u[m][nn][rg + 1] * bf2f(pv >> 16);
            }
        }
#pragma unroll
    for (int nn = 0; nn < 2; ++nn) {
        qq[nn] += __shfl_xor(qq[nn], 16); qq[nn] += __shfl_xor(qq[nn], 32);
    }
    float w1a = w1g[i * 32 + lw], w1b = w1g[i * 32 + 16 + lw];
    float s0 = nm[0] / fmaxf(w1a * sqrtf(fmaxf(qq[0], 0.f)), EPSF * dn[0]);
    float s1 = nm[1] / fmaxf(w1b * sqrtf(fmaxf(qq[1], 0.f)), EPSF * dn[1]);
    float m2 = fmaxf(s0, s1);
    m2 = fmaxf(m2, __shfl_xor(m2, 1)); m2 = fmaxf(m2, __shfl_xor(m2, 2));
    m2 = fmaxf(m2, __shfl_xor(m2, 4)); m2 = fmaxf(m2, __shfl_xor(m2, 8));
    float ssum = __expf(LAM_LSE * (s0 - m2)) + __expf(LAM_LSE * (s1 - m2));
    ssum += __shfl_xor(ssum, 1); ssum += __shfl_xor(ssum, 2);
    ssum += __shfl_xor(ssum, 4); ssum += __shfl_xor(ssum, 8);
    if (l == 0) scores[p] = m2 + logf(ssum) / LAM_LSE;
#undef AV
}

// ---- final hinge loss: 1024 threads, 4-way split per row/col (serial depth 32) ----
__global__ __launch_bounds__(1024) void loss_kernel(const float* __restrict__ scores,
                                                    float* __restrict__ out) {
    __shared__ float diag[NJ];
    __shared__ float part[1024];
    __shared__ float red[256];
    const int tid = threadIdx.x;
    if (tid < NJ) diag[tid] = scores[tid * NI + tid];
    __syncthreads();
    const int unit = tid >> 2, q = tid & 3;
    float m = 0.f;   // clip(...,0) + zeroed diagonal => max starts at 0
    if (unit < 128) {
        const int a = unit;
        const float da = diag[a];
        for (int k = 0; k < 32; ++k) {
            int b = q * 32 + k;
            float c = MARGIN + scores[a * NI + b] - da;
            if (b != a) m = fmaxf(m, c);
        }
    } else {
        const int b = unit - 128;
        const float db = diag[b];
        for (int k = 0; k < 32; ++k) {
            int a = q * 32 + k;
            float c = MARGIN + scores[a * NI + b] - db;
            if (a != b) m = fmaxf(m, c);
        }
    }
    part[tid] = m;
    __syncthreads();
    if (q == 0)
        red[unit] = fmaxf(fmaxf(part[tid], part[tid + 1]), fmaxf(part[tid + 2], part[tid + 3]));
    __syncthreads();
    for (int st = 128; st > 0; st >>= 1) {
        if (tid < st) red[tid] += red[tid + st];
        __syncthreads();
    }
    if (tid == 0) out[0] = red[0];
}

extern "C" void kernel_launch(void* const* d_in, const int* in_sizes, int n_in,
                              void* d_out, int out_size, void* d_ws, size_t ws_size,
                              hipStream_t stream) {
    const float* im = (const float*)d_in[0];
    const float* s = (const float*)d_in[1];

    unsigned short* imsw = (unsigned short*)d_ws;
    unsigned short* ssw = imsw + IM_ELEMS;
    unsigned short* Gswp = ssw + S_ELEMS;
    float* w1 = (float*)(Gswp + GSW_ELEMS);
    float* scores = w1 + S_ROWS;
    unsigned* C = (unsigned*)(scores + NJ * NI);

    hipFuncSetAttribute((const void*)pairG_kernel,
                        hipFuncAttributeMaxDynamicSharedMemorySize, G_SMEM);
    hipFuncSetAttribute((const void*)gram4_kernel,
                        hipFuncAttributeMaxDynamicSharedMemorySize, GRAM_SMEM);

    cvtswz2_kernel<<<dim3(ALL_ROWS / 2), dim3(256), 0, stream>>>(im, s, imsw, w1);
    gram4_kernel<<<dim3(NJ), dim3(512), GRAM_SMEM, stream>>>(imsw, Gswp);
    pairG_kernel<<<dim3(NI / 8, NJ / 8), dim3(512), G_SMEM, stream>>>(imsw, ssw, C);
    pairE_kernel<<<dim3(NI / 8, NJ), dim3(512), 0, stream>>>(C, Gswp, w1, scores);
    loss_kernel<<<dim3(1), dim3(1024), 0, stream>>>(scores, (float*)d_out);
}